// Round 14
// baseline (552.667 us; speedup 1.0000x reference)
//
#include <hip/hip_runtime.h>
#include <cstdint>
#include <math.h>

// Transformer block: LN1 -> QKV -> fused MHA (attn probs = output[1]) -> proj+res
//                    -> LN2 -> GELU MLP + res -> output[0]
// GEMMs: fp16 MFMA 16x16x32, 128x128 tiles, BK=64, global_load_lds width-16
// staging, XOR chunk swizzle (pre-swizzled global source + swizzled ds_read).
// attn: 32 q-rows/block, 512 threads / 8 waves (R13 post-mortem: latency-bound
// at 3.4 waves/CU; this doubles resident waves at UNCHANGED K/V reuse per
// block — R12 showed shrinking the tile instead loses more to L2 re-reads).

typedef _Float16 f16;
typedef _Float16 f16x4 __attribute__((ext_vector_type(4)));
typedef _Float16 f16x8 __attribute__((ext_vector_type(8)));
typedef float f32x4 __attribute__((ext_vector_type(4)));

#define DEV static __device__ __forceinline__

DEV void gload16(const void* g, void* l) {
  __builtin_amdgcn_global_load_lds(
      (__attribute__((address_space(1))) void*)(uintptr_t)g,
      (__attribute__((address_space(3))) void*)(uintptr_t)l, 16, 0, 0);
}

DEV f32x4 mfma16(f16x8 a, f16x8 b, f32x4 c) {
  return __builtin_amdgcn_mfma_f32_16x16x32_f16(a, b, c, 0, 0, 0);
}

// gelu via Abramowitz-Stegun 7.1.26 erf (|err| <= 1.5e-7)
DEV float gelu_f(float v) {
  const float a = fabsf(v) * 0.70710678118654752f;
  const float t = 1.0f / (1.0f + 0.3275911f * a);
  const float p = t * (0.254829592f + t * (-0.284496736f + t * (1.421413741f +
                  t * (-1.453152027f + t * 1.061405429f))));
  const float e = p * __expf(-a * a);
  const float erfv = v >= 0.f ? (1.f - e) : (e - 1.f);
  return 0.5f * v * (1.0f + erfv);
}

// ===== 128x128 NT GEMM core, BK=64: C_tile = A[128,K] * B[128,K]^T =========
DEV void nt_core64(const f16* __restrict__ A, const f16* __restrict__ B,
                   size_t lda, size_t ldb, int K, f16* As, f16* Bs,
                   f32x4 acc[4][4])
{
  const int tid  = threadIdx.x;
  const int lane = tid & 63;
  const int w    = tid >> 6;
  const int wm   = (w >> 1) << 6;
  const int wn   = (w & 1) << 6;
  const int frow = lane & 15;
  const int lg   = lane >> 4;

  const int srow0 = w * 32 + (lane >> 3);
  const int scol  = ((lane & 7) ^ ((lane >> 3) & 7)) << 3;
  const f16* Ab = A + (size_t)srow0 * lda + scol;
  const f16* Bb = B + (size_t)srow0 * ldb + scol;
  f16* la = As + w * 2048 + lane * 8;
  f16* lb = Bs + w * 2048 + lane * 8;

  for (int k0 = 0; k0 < K; k0 += 64) {
#pragma unroll
    for (int L = 0; L < 4; ++L)
      gload16(Ab + (size_t)(L * 8) * lda + k0, la + L * 512);
#pragma unroll
    for (int L = 0; L < 4; ++L)
      gload16(Bb + (size_t)(L * 8) * ldb + k0, lb + L * 512);
    __syncthreads();
#pragma unroll
    for (int kc = 0; kc < 2; ++kc) {
      f16x8 af[4], bf[4];
#pragma unroll
      for (int i = 0; i < 4; ++i) {
        const int ra = wm + i * 16 + frow;
        const int rb = wn + i * 16 + frow;
        af[i] = *(const f16x8*)(As + ra * 64 + ((((kc << 2) + lg) ^ (ra & 7)) << 3));
        bf[i] = *(const f16x8*)(Bs + rb * 64 + ((((kc << 2) + lg) ^ (rb & 7)) << 3));
      }
#pragma unroll
      for (int i = 0; i < 4; ++i)
#pragma unroll
        for (int j = 0; j < 4; ++j)
          acc[i][j] = mfma16(af[i], bf[j], acc[i][j]);
    }
    __syncthreads();
  }
}

// ------- fused: fp32->fp16 weight convert (blocks 0..12287) + LN1 (rest) ----
__global__ __launch_bounds__(256) void k_cvt_ln(const float* __restrict__ s0,
                                                const float* __restrict__ s1,
                                                const float* __restrict__ s2,
                                                const float* __restrict__ s3,
                                                f16* __restrict__ wout,
                                                const float* __restrict__ xin,
                                                const float* __restrict__ g,
                                                const float* __restrict__ bb,
                                                f16* __restrict__ xnout)
{
  __shared__ float red[8];
  const int tid = threadIdx.x;
  if (blockIdx.x < 12288) {
    const int i = blockIdx.x * 256 + tid;
    const float* src;
    int off;
    if (i < 786432)       { src = s0; off = 0; }
    else if (i < 1048576) { src = s1; off = 786432; }
    else if (i < 2097152) { src = s2; off = 1048576; }
    else                  { src = s3; off = 2097152; }
    const float4 f = ((const float4*)src)[i - off];
    f16x4 o; o[0] = (f16)f.x; o[1] = (f16)f.y; o[2] = (f16)f.z; o[3] = (f16)f.w;
    ((f16x4*)wout)[i] = o;
    return;
  }
  const size_t row = blockIdx.x - 12288;
  const float4 v = ((const float4*)(xin + row * 1024))[tid];
  float s  = v.x + v.y + v.z + v.w;
  float sq = v.x * v.x + v.y * v.y + v.z * v.z + v.w * v.w;
#pragma unroll
  for (int off = 32; off > 0; off >>= 1) { s += __shfl_xor(s, off); sq += __shfl_xor(sq, off); }
  if ((tid & 63) == 0) { red[tid >> 6] = s; red[4 + (tid >> 6)] = sq; }
  __syncthreads();
  s  = red[0] + red[1] + red[2] + red[3];
  sq = red[4] + red[5] + red[6] + red[7];
  const float mu = s * (1.0f / 1024.0f);
  const float rs = rsqrtf(sq * (1.0f / 1024.0f) - mu * mu + 1e-5f);
  const float4 gg = ((const float4*)g)[tid];
  const float4 bv = ((const float4*)bb)[tid];
  f16x4 o;
  o[0] = (f16)((v.x - mu) * rs * gg.x + bv.x);
  o[1] = (f16)((v.y - mu) * rs * gg.y + bv.y);
  o[2] = (f16)((v.z - mu) * rs * gg.z + bv.z);
  o[3] = (f16)((v.w - mu) * rs * gg.w + bv.w);
  ((f16x4*)(xnout + row * 1024))[tid] = o;
}

// ---------------- LayerNorm (1024 cols, 1 row/block) ----------------
__global__ __launch_bounds__(256) void k_ln(const float* __restrict__ xin,
                                            const float* __restrict__ g,
                                            const float* __restrict__ bb,
                                            f16* __restrict__ out)
{
  __shared__ float red[8];
  const int tid = threadIdx.x;
  const size_t row = blockIdx.x;
  const float4 v = ((const float4*)(xin + row * 1024))[tid];
  float s  = v.x + v.y + v.z + v.w;
  float sq = v.x * v.x + v.y * v.y + v.z * v.z + v.w * v.w;
#pragma unroll
  for (int off = 32; off > 0; off >>= 1) { s += __shfl_xor(s, off); sq += __shfl_xor(sq, off); }
  if ((tid & 63) == 0) { red[tid >> 6] = s; red[4 + (tid >> 6)] = sq; }
  __syncthreads();
  s  = red[0] + red[1] + red[2] + red[3];
  sq = red[4] + red[5] + red[6] + red[7];
  const float mu = s * (1.0f / 1024.0f);
  const float rs = rsqrtf(sq * (1.0f / 1024.0f) - mu * mu + 1e-5f);
  const float4 gg = ((const float4*)g)[tid];
  const float4 bv = ((const float4*)bb)[tid];
  f16x4 o;
  o[0] = (f16)((v.x - mu) * rs * gg.x + bv.x);
  o[1] = (f16)((v.y - mu) * rs * gg.y + bv.y);
  o[2] = (f16)((v.z - mu) * rs * gg.z + bv.z);
  o[3] = (f16)((v.w - mu) * rs * gg.w + bv.w);
  ((f16x4*)(out + row * 1024))[tid] = o;
}

// ---------------- QKV GEMM: [8192,1024] x [3072,1024]^T ----------------
__global__ __launch_bounds__(256) void k_qkv(const f16* __restrict__ xn,
                                             const f16* __restrict__ wq,
                                             f16* __restrict__ qb, f16* __restrict__ kb,
                                             f16* __restrict__ vT)
{
  __shared__ __align__(16) f16 As[8192], Bs[8192];
  f32x4 acc[4][4] = {};
  const int bm = blockIdx.x, bn = blockIdx.y;
  nt_core64(xn + (size_t)bm * 128 * 1024, wq + (size_t)bn * 128 * 1024,
            1024, 1024, 1024, As, Bs, acc);
  const int tid = threadIdx.x, lane = tid & 63, w = tid >> 6;
  const int r0 = bm * 128 + ((w >> 1) << 6) + ((lane >> 4) << 2);
  const int c0 = bn * 128 + ((w & 1) << 6);
  const int sec = (bn * 128) >> 10;
#pragma unroll
  for (int i = 0; i < 4; ++i) {
#pragma unroll
    for (int j = 0; j < 4; ++j) {
      const int o = c0 + j * 16 + (lane & 15);
      const int h = (o & 1023) >> 6, d = o & 63;
#pragma unroll
      for (int e = 0; e < 4; ++e) {
        const int m = r0 + i * 16 + e;
        const int b = m >> 10, n = m & 1023;
        const int bh = (b << 4) + h;
        const f16 val = (f16)acc[i][j][e];
        if (sec == 0)      qb[((size_t)bh * 1024 + n) * 64 + d] = val;
        else if (sec == 1) kb[((size_t)bh * 1024 + n) * 64 + d] = val;
        else               vT[((size_t)bh * 64 + d) * 1024 + n] = val;
      }
    }
  }
}

// ------- fused attention: 32 q-rows/block, 512 threads / 8 waves ------------
// LDS P[32][1024] fp16, chunk-swizzled: (r,c) at r*1024 + (((c>>3)^(r&7))<<3)+(c&7)
// phase1: wave w owns kv-cols [w*128, w*128+128). phase2: 16 threads/row.
// phase3: wave w -> q-subtile i=(w>>2), d-group (w&3)*16.
__global__ __launch_bounds__(512, 4) void k_attn(const f16* __restrict__ qb,
                                                 const f16* __restrict__ kb,
                                                 const f16* __restrict__ vT,
                                                 float* __restrict__ attn,
                                                 f16* __restrict__ y2)
{
  __shared__ __align__(16) f16 P[32 * 1024];   // 64 KB
  const int tid = threadIdx.x, lane = tid & 63, w = tid >> 6;
  const int lr = lane & 15, lg = lane >> 4;
  const int flat = blockIdx.y * 32 + blockIdx.x;
  const int id2 = (flat & 7) * 512 + (flat >> 3);       // XCD-chunked, bijective
  const int bh = id2 >> 5;
  const int m0 = (id2 & 31) * 32;
  const f16* Qb = qb + ((size_t)bh << 16);
  const f16* Kb = kb + ((size_t)bh << 16);
  const f16* Vt = vT + ((size_t)bh << 16);

  f16x8 qf[2][2];
#pragma unroll
  for (int i = 0; i < 2; ++i)
#pragma unroll
    for (int ks = 0; ks < 2; ++ks)
      qf[i][ks] = *(const f16x8*)(Qb + (size_t)(m0 + i * 16 + lr) * 64 + ks * 32 + lg * 8);

  // phase 1: S = Q K^T * 0.125 -> P_lds. wave w: cols [w*128, w*128+128)
#pragma unroll
  for (int cc = 0; cc < 2; ++cc) {
    const int cb = (w << 7) + (cc << 6);
    f16x8 bf[4][2];
#pragma unroll
    for (int j = 0; j < 4; ++j)
#pragma unroll
      for (int ks = 0; ks < 2; ++ks)
        bf[j][ks] = *(const f16x8*)(Kb + (size_t)(cb + j * 16 + lr) * 64 + ks * 32 + lg * 8);
    f32x4 acc[2][4] = {};
#pragma unroll
    for (int i = 0; i < 2; ++i)
#pragma unroll
      for (int j = 0; j < 4; ++j) {
        acc[i][j] = mfma16(qf[i][0], bf[j][0], acc[i][j]);
        acc[i][j] = mfma16(qf[i][1], bf[j][1], acc[i][j]);
      }
#pragma unroll
    for (int i = 0; i < 2; ++i)
#pragma unroll
      for (int j = 0; j < 4; ++j)
#pragma unroll
        for (int e = 0; e < 4; ++e) {
          const int r = i * 16 + (lg << 2) + e;
          const int c = cb + j * 16 + lr;
          P[(r << 10) + (((c >> 3) ^ (r & 7)) << 3) + (c & 7)] = (f16)(acc[i][j][e] * 0.125f);
        }
  }
  __syncthreads();

  // phase 2: softmax. thread t: row t>>4, 8 chunks (t&15)+16q
  const int r2 = tid >> 4;
  f16* Prow = P + (r2 << 10);
  const int rx = r2 & 7;
  f16x8 vv[8];
  float mrow = -1e30f;
#pragma unroll
  for (int q = 0; q < 8; ++q) {
    const int c = (tid & 15) + (q << 4);
    vv[q] = *(const f16x8*)(Prow + ((c ^ rx) << 3));
#pragma unroll
    for (int e = 0; e < 8; ++e) mrow = fmaxf(mrow, (float)vv[q][e]);
  }
  mrow = fmaxf(mrow, __shfl_xor(mrow, 1));
  mrow = fmaxf(mrow, __shfl_xor(mrow, 2));
  mrow = fmaxf(mrow, __shfl_xor(mrow, 4));
  mrow = fmaxf(mrow, __shfl_xor(mrow, 8));
  float ssum = 0.f;
#pragma unroll
  for (int q = 0; q < 8; ++q) {
#pragma unroll
    for (int e = 0; e < 8; ++e) {
      const float ev = __expf((float)vv[q][e] - mrow);
      ssum += ev;
      vv[q][e] = (f16)ev;
    }
  }
  ssum += __shfl_xor(ssum, 1);
  ssum += __shfl_xor(ssum, 2);
  ssum += __shfl_xor(ssum, 4);
  ssum += __shfl_xor(ssum, 8);
  const float inv = 1.0f / ssum;
  float* Aout = attn + ((size_t)bh << 20) + ((size_t)(m0 + r2) << 10);
#pragma unroll
  for (int q = 0; q < 8; ++q) {
    const int c = (tid & 15) + (q << 4);
    f16x8 nv;
    f32x4 o0, o1;
    o0[0] = (float)vv[q][0] * inv; o0[1] = (float)vv[q][1] * inv;
    o0[2] = (float)vv[q][2] * inv; o0[3] = (float)vv[q][3] * inv;
    o1[0] = (float)vv[q][4] * inv; o1[1] = (float)vv[q][5] * inv;
    o1[2] = (float)vv[q][6] * inv; o1[3] = (float)vv[q][7] * inv;
#pragma unroll
    for (int e = 0; e < 8; ++e) nv[e] = (f16)((float)vv[q][e] * inv);
    __builtin_nontemporal_store(o0, (f32x4*)(Aout + (c << 3)));
    __builtin_nontemporal_store(o1, (f32x4*)(Aout + (c << 3)) + 1);
    *(f16x8*)(Prow + ((c ^ rx) << 3)) = nv;
  }
  __syncthreads();

  // phase 3: y = P @ V. wave w: q-subtile i=w>>2, d-cols [(w&3)*16, +16).
  const int i3 = w >> 2;
  const int dc = (w & 3) << 4;
  const int ra = i3 * 16 + lr;
  f32x4 acc2 = {};
#pragma unroll 4
  for (int k0 = 0; k0 < 1024; k0 += 32) {
    const f16x8 bf = *(const f16x8*)(Vt + (size_t)(dc + lr) * 1024 + k0 + lg * 8);
    const f16x8 af = *(const f16x8*)(P + (ra << 10) + ((((k0 >> 3) + lg) ^ (ra & 7)) << 3));
    acc2 = mfma16(af, bf, acc2);
  }
  const int b = bh >> 4, h = bh & 15;
#pragma unroll
  for (int e = 0; e < 4; ++e) {
    const int rloc = i3 * 16 + (lg << 2) + e;
    y2[(size_t)(b * 1024 + m0 + rloc) * 1024 + (h << 6) + dc + lr] = (f16)acc2[e];
  }
}

// ---------------- proj: xmid = y2 @ wproj^T + bproj + x ----------------
__global__ __launch_bounds__(256) void k_proj(const f16* __restrict__ y2,
                                              const f16* __restrict__ wp,
                                              const float* __restrict__ bproj,
                                              const float* __restrict__ x,
                                              float* __restrict__ xmid)
{
  __shared__ __align__(16) f16 As[8192], Bs[8192];
  f32x4 acc[4][4] = {};
  nt_core64(y2 + (size_t)blockIdx.x * 128 * 1024, wp + (size_t)blockIdx.y * 128 * 1024,
            1024, 1024, 1024, As, Bs, acc);
  const int tid = threadIdx.x, lane = tid & 63, w = tid >> 6;
  const int r0 = blockIdx.x * 128 + ((w >> 1) << 6) + ((lane >> 4) << 2);
  const int c0 = blockIdx.y * 128 + ((w & 1) << 6) + (lane & 15);
#pragma unroll
  for (int i = 0; i < 4; ++i)
#pragma unroll
    for (int j = 0; j < 4; ++j) {
      const int c = c0 + j * 16;
      const float bias = bproj[c];
#pragma unroll
      for (int e = 0; e < 4; ++e) {
        const size_t idx = (size_t)(r0 + i * 16 + e) * 1024 + c;
        xmid[idx] = acc[i][j][e] + bias + x[idx];
      }
    }
}

// ---------------- fc1: h = gelu(xn2 @ wfc1^T + bfc1) ----------------
__global__ __launch_bounds__(256) void k_fc1(const f16* __restrict__ xn,
                                             const f16* __restrict__ wf,
                                             const float* __restrict__ bfc1,
                                             f16* __restrict__ hb)
{
  __shared__ __align__(16) f16 As[8192], Bs[8192];
  f32x4 acc[4][4] = {};
  nt_core64(xn + (size_t)blockIdx.x * 128 * 1024, wf + (size_t)blockIdx.y * 128 * 1024,
            1024, 1024, 1024, As, Bs, acc);
  const int tid = threadIdx.x, lane = tid & 63, w = tid >> 6;
  const int r0 = blockIdx.x * 128 + ((w >> 1) << 6) + ((lane >> 4) << 2);
  const int c0 = blockIdx.y * 128 + ((w & 1) << 6) + (lane & 15);
#pragma unroll
  for (int i = 0; i < 4; ++i)
#pragma unroll
    for (int j = 0; j < 4; ++j) {
      const int c = c0 + j * 16;
      const float bias = bfc1[c];
#pragma unroll
      for (int e = 0; e < 4; ++e) {
        const float t = acc[i][j][e] + bias;
        hb[(size_t)(r0 + i * 16 + e) * 4096 + c] = (f16)gelu_f(t);
      }
    }
}

// ---------------- fc2: out = h @ wfc2^T + bfc2 + xmid ----------------
__global__ __launch_bounds__(256) void k_fc2(const f16* __restrict__ hb,
                                             const f16* __restrict__ wf,
                                             const float* __restrict__ bfc2,
                                             const float* __restrict__ xmid,
                                             float* __restrict__ out)
{
  __shared__ __align__(16) f16 As[8192], Bs[8192];
  f32x4 acc[4][4] = {};
  nt_core64(hb + (size_t)blockIdx.x * 128 * 4096, wf + (size_t)blockIdx.y * 128 * 4096,
            4096, 4096, 4096, As, Bs, acc);
  const int tid = threadIdx.x, lane = tid & 63, w = tid >> 6;
  const int r0 = blockIdx.x * 128 + ((w >> 1) << 6) + ((lane >> 4) << 2);
  const int c0 = blockIdx.y * 128 + ((w & 1) << 6) + (lane & 15);
#pragma unroll
  for (int i = 0; i < 4; ++i)
#pragma unroll
    for (int j = 0; j < 4; ++j) {
      const int c = c0 + j * 16;
      const float bias = bfc2[c];
#pragma unroll
      for (int e = 0; e < 4; ++e) {
        const size_t idx = (size_t)(r0 + i * 16 + e) * 1024 + c;
        out[idx] = acc[i][j][e] + bias + xmid[idx];
      }
    }
}

extern "C" void kernel_launch(void* const* d_in, const int* in_sizes, int n_in,
                              void* d_out, int out_size, void* d_ws, size_t ws_size,
                              hipStream_t stream)
{
  const float* x     = (const float*)d_in[0];
  const float* ln1g  = (const float*)d_in[1];
  const float* ln1b  = (const float*)d_in[2];
  const float* wqkv  = (const float*)d_in[3];
  const float* wproj = (const float*)d_in[4];
  const float* bproj = (const float*)d_in[5];
  const float* ln2g  = (const float*)d_in[6];
  const float* ln2b  = (const float*)d_in[7];
  const float* wfc1  = (const float*)d_in[8];
  const float* bfc1  = (const float*)d_in[9];
  const float* wfc2  = (const float*)d_in[10];
  const float* bfc2  = (const float*)d_in[11];

  char* ws = (char*)d_ws;
  f16* wqkv_h  = (f16*)(ws);                    //  6 MB  (contiguous cvt dest)
  f16* wproj_h = (f16*)(ws + 6291456);          //  2 MB
  f16* wfc1_h  = (f16*)(ws + 8388608);          //  8 MB
  f16* wfc2_h  = (f16*)(ws + 16777216);         //  8 MB
  f16* xn      = (f16*)(ws + 25165824);         // 16 MB (xn1, reused as xn2)
  f16* qb      = (f16*)(ws + 41943040);         // 16 MB
  f16* kb      = (f16*)(ws + 58720256);         // 16 MB
  f16* vT      = (f16*)(ws + 75497472);         // 16 MB
  f16* y2      = (f16*)(ws + 92274688);         // 16 MB
  float* xmid  = (float*)(ws + 109051904);      // 32 MB
  f16* hb      = (f16*)(ws + 41943040);         // 64 MB, aliases qb..y2 (dead by fc1)

  float* out_x = (float*)d_out;
  float* attn  = (float*)d_out + 8388608;

  k_cvt_ln<<<12288 + 8192, 256, 0, stream>>>(wqkv, wproj, wfc1, wfc2, wqkv_h,
                                             x, ln1g, ln1b, xn);
  k_qkv<<<dim3(64, 24), 256, 0, stream>>>(xn, wqkv_h, qb, kb, vT);
  k_attn<<<dim3(32, 128), 512, 0, stream>>>(qb, kb, vT, attn, y2);
  k_proj<<<dim3(64, 8), 256, 0, stream>>>(y2, wproj_h, bproj, x, xmid);
  k_ln<<<8192, 256, 0, stream>>>(xmid, ln2g, ln2b, xn);
  k_fc1<<<dim3(64, 32), 256, 0, stream>>>(xn, wfc1_h, bfc1, hb);
  k_fc2<<<dim3(64, 8), 256, 0, stream>>>(hb, wfc2_h, bfc2, xmid, out_x);
}

// Round 15
// 548.384 us; speedup vs baseline: 1.0078x; 1.0078x over previous
//
#include <hip/hip_runtime.h>
#include <cstdint>
#include <math.h>

// Transformer block: LN1 -> QKV -> fused MHA (attn probs = output[1]) -> proj+res
//                    -> LN2 -> GELU MLP + res -> output[0]
// GEMMs: fp16 MFMA 16x16x32, 128x128 tiles, BK=64, global_load_lds width-16
// staging, XOR chunk swizzle (pre-swizzled global source + swizzled ds_read).
// attn: 32 q-rows/block, 256 threads (R6 geometry — best known). The 537MB
// fp32 attn-output store is issued INSIDE the PV loop, after the barrier:
// stores before a barrier force a vmcnt(0) drain (R8 profile: writes at only
// 2.9 TB/s, 340us). Interleaved after each V load they drain under compute.

typedef _Float16 f16;
typedef _Float16 f16x4 __attribute__((ext_vector_type(4)));
typedef _Float16 f16x8 __attribute__((ext_vector_type(8)));
typedef float f32x4 __attribute__((ext_vector_type(4)));

#define DEV static __device__ __forceinline__

DEV void gload16(const void* g, void* l) {
  __builtin_amdgcn_global_load_lds(
      (__attribute__((address_space(1))) void*)(uintptr_t)g,
      (__attribute__((address_space(3))) void*)(uintptr_t)l, 16, 0, 0);
}

DEV f32x4 mfma16(f16x8 a, f16x8 b, f32x4 c) {
  return __builtin_amdgcn_mfma_f32_16x16x32_f16(a, b, c, 0, 0, 0);
}

// gelu via Abramowitz-Stegun 7.1.26 erf (|err| <= 1.5e-7)
DEV float gelu_f(float v) {
  const float a = fabsf(v) * 0.70710678118654752f;
  const float t = 1.0f / (1.0f + 0.3275911f * a);
  const float p = t * (0.254829592f + t * (-0.284496736f + t * (1.421413741f +
                  t * (-1.453152027f + t * 1.061405429f))));
  const float e = p * __expf(-a * a);
  const float erfv = v >= 0.f ? (1.f - e) : (e - 1.f);
  return 0.5f * v * (1.0f + erfv);
}

// ===== 128x128 NT GEMM core, BK=64: C_tile = A[128,K] * B[128,K]^T =========
DEV void nt_core64(const f16* __restrict__ A, const f16* __restrict__ B,
                   size_t lda, size_t ldb, int K, f16* As, f16* Bs,
                   f32x4 acc[4][4])
{
  const int tid  = threadIdx.x;
  const int lane = tid & 63;
  const int w    = tid >> 6;
  const int wm   = (w >> 1) << 6;
  const int wn   = (w & 1) << 6;
  const int frow = lane & 15;
  const int lg   = lane >> 4;

  const int srow0 = w * 32 + (lane >> 3);
  const int scol  = ((lane & 7) ^ ((lane >> 3) & 7)) << 3;
  const f16* Ab = A + (size_t)srow0 * lda + scol;
  const f16* Bb = B + (size_t)srow0 * ldb + scol;
  f16* la = As + w * 2048 + lane * 8;
  f16* lb = Bs + w * 2048 + lane * 8;

  for (int k0 = 0; k0 < K; k0 += 64) {
#pragma unroll
    for (int L = 0; L < 4; ++L)
      gload16(Ab + (size_t)(L * 8) * lda + k0, la + L * 512);
#pragma unroll
    for (int L = 0; L < 4; ++L)
      gload16(Bb + (size_t)(L * 8) * ldb + k0, lb + L * 512);
    __syncthreads();
#pragma unroll
    for (int kc = 0; kc < 2; ++kc) {
      f16x8 af[4], bf[4];
#pragma unroll
      for (int i = 0; i < 4; ++i) {
        const int ra = wm + i * 16 + frow;
        const int rb = wn + i * 16 + frow;
        af[i] = *(const f16x8*)(As + ra * 64 + ((((kc << 2) + lg) ^ (ra & 7)) << 3));
        bf[i] = *(const f16x8*)(Bs + rb * 64 + ((((kc << 2) + lg) ^ (rb & 7)) << 3));
      }
#pragma unroll
      for (int i = 0; i < 4; ++i)
#pragma unroll
        for (int j = 0; j < 4; ++j)
          acc[i][j] = mfma16(af[i], bf[j], acc[i][j]);
    }
    __syncthreads();
  }
}

// ------- fused: fp32->fp16 weight convert (blocks 0..12287) + LN1 (rest) ----
__global__ __launch_bounds__(256) void k_cvt_ln(const float* __restrict__ s0,
                                                const float* __restrict__ s1,
                                                const float* __restrict__ s2,
                                                const float* __restrict__ s3,
                                                f16* __restrict__ wout,
                                                const float* __restrict__ xin,
                                                const float* __restrict__ g,
                                                const float* __restrict__ bb,
                                                f16* __restrict__ xnout)
{
  __shared__ float red[8];
  const int tid = threadIdx.x;
  if (blockIdx.x < 12288) {
    const int i = blockIdx.x * 256 + tid;
    const float* src;
    int off;
    if (i < 786432)       { src = s0; off = 0; }
    else if (i < 1048576) { src = s1; off = 786432; }
    else if (i < 2097152) { src = s2; off = 1048576; }
    else                  { src = s3; off = 2097152; }
    const float4 f = ((const float4*)src)[i - off];
    f16x4 o; o[0] = (f16)f.x; o[1] = (f16)f.y; o[2] = (f16)f.z; o[3] = (f16)f.w;
    ((f16x4*)wout)[i] = o;
    return;
  }
  const size_t row = blockIdx.x - 12288;
  const float4 v = ((const float4*)(xin + row * 1024))[tid];
  float s  = v.x + v.y + v.z + v.w;
  float sq = v.x * v.x + v.y * v.y + v.z * v.z + v.w * v.w;
#pragma unroll
  for (int off = 32; off > 0; off >>= 1) { s += __shfl_xor(s, off); sq += __shfl_xor(sq, off); }
  if ((tid & 63) == 0) { red[tid >> 6] = s; red[4 + (tid >> 6)] = sq; }
  __syncthreads();
  s  = red[0] + red[1] + red[2] + red[3];
  sq = red[4] + red[5] + red[6] + red[7];
  const float mu = s * (1.0f / 1024.0f);
  const float rs = rsqrtf(sq * (1.0f / 1024.0f) - mu * mu + 1e-5f);
  const float4 gg = ((const float4*)g)[tid];
  const float4 bv = ((const float4*)bb)[tid];
  f16x4 o;
  o[0] = (f16)((v.x - mu) * rs * gg.x + bv.x);
  o[1] = (f16)((v.y - mu) * rs * gg.y + bv.y);
  o[2] = (f16)((v.z - mu) * rs * gg.z + bv.z);
  o[3] = (f16)((v.w - mu) * rs * gg.w + bv.w);
  ((f16x4*)(xnout + row * 1024))[tid] = o;
}

// ---------------- LayerNorm (1024 cols, 1 row/block) ----------------
__global__ __launch_bounds__(256) void k_ln(const float* __restrict__ xin,
                                            const float* __restrict__ g,
                                            const float* __restrict__ bb,
                                            f16* __restrict__ out)
{
  __shared__ float red[8];
  const int tid = threadIdx.x;
  const size_t row = blockIdx.x;
  const float4 v = ((const float4*)(xin + row * 1024))[tid];
  float s  = v.x + v.y + v.z + v.w;
  float sq = v.x * v.x + v.y * v.y + v.z * v.z + v.w * v.w;
#pragma unroll
  for (int off = 32; off > 0; off >>= 1) { s += __shfl_xor(s, off); sq += __shfl_xor(sq, off); }
  if ((tid & 63) == 0) { red[tid >> 6] = s; red[4 + (tid >> 6)] = sq; }
  __syncthreads();
  s  = red[0] + red[1] + red[2] + red[3];
  sq = red[4] + red[5] + red[6] + red[7];
  const float mu = s * (1.0f / 1024.0f);
  const float rs = rsqrtf(sq * (1.0f / 1024.0f) - mu * mu + 1e-5f);
  const float4 gg = ((const float4*)g)[tid];
  const float4 bv = ((const float4*)bb)[tid];
  f16x4 o;
  o[0] = (f16)((v.x - mu) * rs * gg.x + bv.x);
  o[1] = (f16)((v.y - mu) * rs * gg.y + bv.y);
  o[2] = (f16)((v.z - mu) * rs * gg.z + bv.z);
  o[3] = (f16)((v.w - mu) * rs * gg.w + bv.w);
  ((f16x4*)(out + row * 1024))[tid] = o;
}

// ---------------- QKV GEMM: [8192,1024] x [3072,1024]^T ----------------
__global__ __launch_bounds__(256) void k_qkv(const f16* __restrict__ xn,
                                             const f16* __restrict__ wq,
                                             f16* __restrict__ qb, f16* __restrict__ kb,
                                             f16* __restrict__ vT)
{
  __shared__ __align__(16) f16 As[8192], Bs[8192];
  f32x4 acc[4][4] = {};
  const int bm = blockIdx.x, bn = blockIdx.y;
  nt_core64(xn + (size_t)bm * 128 * 1024, wq + (size_t)bn * 128 * 1024,
            1024, 1024, 1024, As, Bs, acc);
  const int tid = threadIdx.x, lane = tid & 63, w = tid >> 6;
  const int r0 = bm * 128 + ((w >> 1) << 6) + ((lane >> 4) << 2);
  const int c0 = bn * 128 + ((w & 1) << 6);
  const int sec = (bn * 128) >> 10;
#pragma unroll
  for (int i = 0; i < 4; ++i) {
#pragma unroll
    for (int j = 0; j < 4; ++j) {
      const int o = c0 + j * 16 + (lane & 15);
      const int h = (o & 1023) >> 6, d = o & 63;
#pragma unroll
      for (int e = 0; e < 4; ++e) {
        const int m = r0 + i * 16 + e;
        const int b = m >> 10, n = m & 1023;
        const int bh = (b << 4) + h;
        const f16 val = (f16)acc[i][j][e];
        if (sec == 0)      qb[((size_t)bh * 1024 + n) * 64 + d] = val;
        else if (sec == 1) kb[((size_t)bh * 1024 + n) * 64 + d] = val;
        else               vT[((size_t)bh * 64 + d) * 1024 + n] = val;
      }
    }
  }
}

// ------- fused attention: 32 q-rows/block, stores overlapped with PV --------
// LDS P[32][1024] fp16, chunk-swizzled: (r,c) at r*1024 + (((c>>3)^(r&7))<<3)+(c&7)
__global__ __launch_bounds__(256) void k_attn(const f16* __restrict__ qb,
                                              const f16* __restrict__ kb,
                                              const f16* __restrict__ vT,
                                              float* __restrict__ attn,
                                              f16* __restrict__ y2)
{
  __shared__ __align__(16) f16 P[32 * 1024];   // 64 KB
  const int tid = threadIdx.x, lane = tid & 63, w = tid >> 6;
  const int lr = lane & 15, lg = lane >> 4;
  const int flat = blockIdx.y * 32 + blockIdx.x;
  const int id2 = (flat & 7) * 512 + (flat >> 3);       // XCD-chunked, bijective
  const int bh = id2 >> 5;
  const int m0 = (id2 & 31) * 32;
  const f16* Qb = qb + ((size_t)bh << 16);
  const f16* Kb = kb + ((size_t)bh << 16);
  const f16* Vt = vT + ((size_t)bh << 16);

  f16x8 qf[2][2];
#pragma unroll
  for (int i = 0; i < 2; ++i)
#pragma unroll
    for (int ks = 0; ks < 2; ++ks)
      qf[i][ks] = *(const f16x8*)(Qb + (size_t)(m0 + i * 16 + lr) * 64 + ks * 32 + lg * 8);

  // phase 1: S = Q K^T * 0.125 -> P_lds (fp16)
  for (int cc = 0; cc < 4; ++cc) {
    const int cb = (w << 8) + (cc << 6);
    f16x8 bf[4][2];
#pragma unroll
    for (int j = 0; j < 4; ++j)
#pragma unroll
      for (int ks = 0; ks < 2; ++ks)
        bf[j][ks] = *(const f16x8*)(Kb + (size_t)(cb + j * 16 + lr) * 64 + ks * 32 + lg * 8);
    f32x4 acc[2][4] = {};
#pragma unroll
    for (int i = 0; i < 2; ++i)
#pragma unroll
      for (int j = 0; j < 4; ++j) {
        acc[i][j] = mfma16(qf[i][0], bf[j][0], acc[i][j]);
        acc[i][j] = mfma16(qf[i][1], bf[j][1], acc[i][j]);
      }
#pragma unroll
    for (int i = 0; i < 2; ++i)
#pragma unroll
      for (int j = 0; j < 4; ++j)
#pragma unroll
        for (int e = 0; e < 4; ++e) {
          const int r = i * 16 + (lg << 2) + e;
          const int c = cb + j * 16 + lr;
          P[(r << 10) + (((c >> 3) ^ (r & 7)) << 3) + (c & 7)] = (f16)(acc[i][j][e] * 0.125f);
        }
  }
  __syncthreads();

  // phase 2: softmax. thread t: row t>>3, 16 chunks (t&7)+8q. Normalized f16
  // written to LDS (what the barrier must order); raw exp + inv stay in regs;
  // the fp32 global store is deferred into phase 3.
  const int r2 = tid >> 3;
  f16* Prow = P + (r2 << 10);
  const int rx = r2 & 7;
  f16x8 vv[16];
  float mrow = -1e30f;
#pragma unroll
  for (int q = 0; q < 16; ++q) {
    const int c = (tid & 7) + (q << 3);
    vv[q] = *(const f16x8*)(Prow + ((c ^ rx) << 3));
#pragma unroll
    for (int e = 0; e < 8; ++e) mrow = fmaxf(mrow, (float)vv[q][e]);
  }
  mrow = fmaxf(mrow, __shfl_xor(mrow, 1));
  mrow = fmaxf(mrow, __shfl_xor(mrow, 2));
  mrow = fmaxf(mrow, __shfl_xor(mrow, 4));
  float ssum = 0.f;
#pragma unroll
  for (int q = 0; q < 16; ++q) {
#pragma unroll
    for (int e = 0; e < 8; ++e) {
      const float ev = __expf((float)vv[q][e] - mrow);
      ssum += ev;
      vv[q][e] = (f16)ev;
    }
  }
  ssum += __shfl_xor(ssum, 1);
  ssum += __shfl_xor(ssum, 2);
  ssum += __shfl_xor(ssum, 4);
  const float inv = 1.0f / ssum;
#pragma unroll
  for (int q = 0; q < 16; ++q) {
    const int c = (tid & 7) + (q << 3);
    f16x8 nv;
#pragma unroll
    for (int e = 0; e < 8; ++e) nv[e] = (f16)((float)vv[q][e] * inv);
    *(f16x8*)(Prow + ((c ^ rx) << 3)) = nv;
  }
  __syncthreads();

  // phase 3: y = P @ V with the 128KB/block fp32 attn store interleaved.
  // Each store pair is issued AFTER that iteration's V load, so V-use waits
  // (vmcnt is FIFO) never force store completion; stores drain under MFMA.
  float* Aout = attn + ((size_t)bh << 20) + ((size_t)(m0 + r2) << 10);
  const int dc = w << 4;
  f32x4 acc2[2] = {};
#pragma unroll 4
  for (int k0 = 0; k0 < 1024; k0 += 32) {
    const f16x8 bf = *(const f16x8*)(Vt + (size_t)(dc + lr) * 1024 + k0 + lg * 8);
    const int idx = k0 >> 5;
    if (!(idx & 1)) {
      const int q = idx >> 1;
      const int c = (tid & 7) + (q << 3);
      f32x4 o0, o1;
      o0[0] = (float)vv[q][0] * inv; o0[1] = (float)vv[q][1] * inv;
      o0[2] = (float)vv[q][2] * inv; o0[3] = (float)vv[q][3] * inv;
      o1[0] = (float)vv[q][4] * inv; o1[1] = (float)vv[q][5] * inv;
      o1[2] = (float)vv[q][6] * inv; o1[3] = (float)vv[q][7] * inv;
      __builtin_nontemporal_store(o0, (f32x4*)(Aout + (c << 3)));
      __builtin_nontemporal_store(o1, (f32x4*)(Aout + (c << 3)) + 1);
    }
#pragma unroll
    for (int i = 0; i < 2; ++i) {
      const int ra = i * 16 + lr;
      const int ch = (k0 >> 3) + lg;
      const f16x8 af = *(const f16x8*)(P + (ra << 10) + ((ch ^ (ra & 7)) << 3));
      acc2[i] = mfma16(af, bf, acc2[i]);
    }
  }
  const int b = bh >> 4, h = bh & 15;
#pragma unroll
  for (int i = 0; i < 2; ++i)
#pragma unroll
    for (int e = 0; e < 4; ++e) {
      const int rloc = i * 16 + (lg << 2) + e;
      y2[(size_t)(b * 1024 + m0 + rloc) * 1024 + (h << 6) + dc + lr] = (f16)acc2[i][e];
    }
}

// ---------------- proj: xmid = y2 @ wproj^T + bproj + x ----------------
__global__ __launch_bounds__(256) void k_proj(const f16* __restrict__ y2,
                                              const f16* __restrict__ wp,
                                              const float* __restrict__ bproj,
                                              const float* __restrict__ x,
                                              float* __restrict__ xmid)
{
  __shared__ __align__(16) f16 As[8192], Bs[8192];
  f32x4 acc[4][4] = {};
  nt_core64(y2 + (size_t)blockIdx.x * 128 * 1024, wp + (size_t)blockIdx.y * 128 * 1024,
            1024, 1024, 1024, As, Bs, acc);
  const int tid = threadIdx.x, lane = tid & 63, w = tid >> 6;
  const int r0 = blockIdx.x * 128 + ((w >> 1) << 6) + ((lane >> 4) << 2);
  const int c0 = blockIdx.y * 128 + ((w & 1) << 6) + (lane & 15);
#pragma unroll
  for (int i = 0; i < 4; ++i)
#pragma unroll
    for (int j = 0; j < 4; ++j) {
      const int c = c0 + j * 16;
      const float bias = bproj[c];
#pragma unroll
      for (int e = 0; e < 4; ++e) {
        const size_t idx = (size_t)(r0 + i * 16 + e) * 1024 + c;
        xmid[idx] = acc[i][j][e] + bias + x[idx];
      }
    }
}

// ---------------- fc1: h = gelu(xn2 @ wfc1^T + bfc1) ----------------
__global__ __launch_bounds__(256) void k_fc1(const f16* __restrict__ xn,
                                             const f16* __restrict__ wf,
                                             const float* __restrict__ bfc1,
                                             f16* __restrict__ hb)
{
  __shared__ __align__(16) f16 As[8192], Bs[8192];
  f32x4 acc[4][4] = {};
  nt_core64(xn + (size_t)blockIdx.x * 128 * 1024, wf + (size_t)blockIdx.y * 128 * 1024,
            1024, 1024, 1024, As, Bs, acc);
  const int tid = threadIdx.x, lane = tid & 63, w = tid >> 6;
  const int r0 = blockIdx.x * 128 + ((w >> 1) << 6) + ((lane >> 4) << 2);
  const int c0 = blockIdx.y * 128 + ((w & 1) << 6) + (lane & 15);
#pragma unroll
  for (int i = 0; i < 4; ++i)
#pragma unroll
    for (int j = 0; j < 4; ++j) {
      const int c = c0 + j * 16;
      const float bias = bfc1[c];
#pragma unroll
      for (int e = 0; e < 4; ++e) {
        const float t = acc[i][j][e] + bias;
        hb[(size_t)(r0 + i * 16 + e) * 4096 + c] = (f16)gelu_f(t);
      }
    }
}

// ---------------- fc2: out = h @ wfc2^T + bfc2 + xmid ----------------
__global__ __launch_bounds__(256) void k_fc2(const f16* __restrict__ hb,
                                             const f16* __restrict__ wf,
                                             const float* __restrict__ bfc2,
                                             const float* __restrict__ xmid,
                                             float* __restrict__ out)
{
  __shared__ __align__(16) f16 As[8192], Bs[8192];
  f32x4 acc[4][4] = {};
  nt_core64(hb + (size_t)blockIdx.x * 128 * 4096, wf + (size_t)blockIdx.y * 128 * 4096,
            4096, 4096, 4096, As, Bs, acc);
  const int tid = threadIdx.x, lane = tid & 63, w = tid >> 6;
  const int r0 = blockIdx.x * 128 + ((w >> 1) << 6) + ((lane >> 4) << 2);
  const int c0 = blockIdx.y * 128 + ((w & 1) << 6) + (lane & 15);
#pragma unroll
  for (int i = 0; i < 4; ++i)
#pragma unroll
    for (int j = 0; j < 4; ++j) {
      const int c = c0 + j * 16;
      const float bias = bfc2[c];
#pragma unroll
      for (int e = 0; e < 4; ++e) {
        const size_t idx = (size_t)(r0 + i * 16 + e) * 1024 + c;
        out[idx] = acc[i][j][e] + bias + xmid[idx];
      }
    }
}

extern "C" void kernel_launch(void* const* d_in, const int* in_sizes, int n_in,
                              void* d_out, int out_size, void* d_ws, size_t ws_size,
                              hipStream_t stream)
{
  const float* x     = (const float*)d_in[0];
  const float* ln1g  = (const float*)d_in[1];
  const float* ln1b  = (const float*)d_in[2];
  const float* wqkv  = (const float*)d_in[3];
  const float* wproj = (const float*)d_in[4];
  const float* bproj = (const float*)d_in[5];
  const float* ln2g  = (const float*)d_in[6];
  const float* ln2b  = (const float*)d_in[7];
  const float* wfc1  = (const float*)d_in[8];
  const float* bfc1  = (const float*)d_in[9];
  const float* wfc2  = (const float*)d_in[10];
  const float* bfc2  = (const float*)d_in[11];

  char* ws = (char*)d_ws;
  f16* wqkv_h  = (f16*)(ws);                    //  6 MB  (contiguous cvt dest)
  f16* wproj_h = (f16*)(ws + 6291456);          //  2 MB
  f16* wfc1_h  = (f16*)(ws + 8388608);          //  8 MB
  f16* wfc2_h  = (f16*)(ws + 16777216);         //  8 MB
  f16* xn      = (f16*)(ws + 25165824);         // 16 MB (xn1, reused as xn2)
  f16* qb      = (f16*)(ws + 41943040);         // 16 MB
  f16* kb      = (f16*)(ws + 58720256);         // 16 MB
  f16* vT      = (f16*)(ws + 75497472);         // 16 MB
  f16* y2      = (f16*)(ws + 92274688);         // 16 MB
  float* xmid  = (float*)(ws + 109051904);      // 32 MB
  f16* hb      = (f16*)(ws + 41943040);         // 64 MB, aliases qb..y2 (dead by fc1)

  float* out_x = (float*)d_out;
  float* attn  = (float*)d_out + 8388608;

  k_cvt_ln<<<12288 + 8192, 256, 0, stream>>>(wqkv, wproj, wfc1, wfc2, wqkv_h,
                                             x, ln1g, ln1b, xn);
  k_qkv<<<dim3(64, 24), 256, 0, stream>>>(xn, wqkv_h, qb, kb, vT);
  k_attn<<<dim3(32, 128), 256, 0, stream>>>(qb, kb, vT, attn, y2);
  k_proj<<<dim3(64, 8), 256, 0, stream>>>(y2, wproj_h, bproj, x, xmid);
  k_ln<<<8192, 256, 0, stream>>>(xmid, ln2g, ln2b, xn);
  k_fc1<<<dim3(64, 32), 256, 0, stream>>>(xn, wfc1_h, bfc1, hb);
  k_fc2<<<dim3(64, 8), 256, 0, stream>>>(hb, wfc2_h, bfc2, xmid, out_x);
}

// Round 16
// 505.869 us; speedup vs baseline: 1.0925x; 1.0840x over previous
//
#include <hip/hip_runtime.h>
#include <cstdint>
#include <math.h>

// Transformer block: LN1 -> QKV -> fused MHA (attn probs = output[1]) -> proj+res
//                    -> LN2 -> GELU MLP + res -> output[0]
// GEMMs: fp16 MFMA 16x16x32, 128x128 tiles, BK=64, global_load_lds width-16
// staging, XOR chunk swizzle (pre-swizzled global source + swizzled ds_read).
// attn: 32 q-rows/block, 256 threads (R6 geometry). The 537MB fp32 attn store
// is issued at the VERY END of the kernel (after PV + y2): R8 profile showed
// the phase2->3 barrier's implicit vmcnt(0) drains 128KB/CU of stores with all
// waves parked (writes at 2.6 TB/s); R15 showed interleaving them into the PV
// loop serializes MFMA on FIFO store retirement. End-of-kernel stores drain
// in the background under other blocks' compute — nothing ever waits on them.

typedef _Float16 f16;
typedef _Float16 f16x4 __attribute__((ext_vector_type(4)));
typedef _Float16 f16x8 __attribute__((ext_vector_type(8)));
typedef float f32x4 __attribute__((ext_vector_type(4)));

#define DEV static __device__ __forceinline__

DEV void gload16(const void* g, void* l) {
  __builtin_amdgcn_global_load_lds(
      (__attribute__((address_space(1))) void*)(uintptr_t)g,
      (__attribute__((address_space(3))) void*)(uintptr_t)l, 16, 0, 0);
}

DEV f32x4 mfma16(f16x8 a, f16x8 b, f32x4 c) {
  return __builtin_amdgcn_mfma_f32_16x16x32_f16(a, b, c, 0, 0, 0);
}

// gelu via Abramowitz-Stegun 7.1.26 erf (|err| <= 1.5e-7)
DEV float gelu_f(float v) {
  const float a = fabsf(v) * 0.70710678118654752f;
  const float t = 1.0f / (1.0f + 0.3275911f * a);
  const float p = t * (0.254829592f + t * (-0.284496736f + t * (1.421413741f +
                  t * (-1.453152027f + t * 1.061405429f))));
  const float e = p * __expf(-a * a);
  const float erfv = v >= 0.f ? (1.f - e) : (e - 1.f);
  return 0.5f * v * (1.0f + erfv);
}

// ===== 128x128 NT GEMM core, BK=64: C_tile = A[128,K] * B[128,K]^T =========
DEV void nt_core64(const f16* __restrict__ A, const f16* __restrict__ B,
                   size_t lda, size_t ldb, int K, f16* As, f16* Bs,
                   f32x4 acc[4][4])
{
  const int tid  = threadIdx.x;
  const int lane = tid & 63;
  const int w    = tid >> 6;
  const int wm   = (w >> 1) << 6;
  const int wn   = (w & 1) << 6;
  const int frow = lane & 15;
  const int lg   = lane >> 4;

  const int srow0 = w * 32 + (lane >> 3);
  const int scol  = ((lane & 7) ^ ((lane >> 3) & 7)) << 3;
  const f16* Ab = A + (size_t)srow0 * lda + scol;
  const f16* Bb = B + (size_t)srow0 * ldb + scol;
  f16* la = As + w * 2048 + lane * 8;
  f16* lb = Bs + w * 2048 + lane * 8;

  for (int k0 = 0; k0 < K; k0 += 64) {
#pragma unroll
    for (int L = 0; L < 4; ++L)
      gload16(Ab + (size_t)(L * 8) * lda + k0, la + L * 512);
#pragma unroll
    for (int L = 0; L < 4; ++L)
      gload16(Bb + (size_t)(L * 8) * ldb + k0, lb + L * 512);
    __syncthreads();
#pragma unroll
    for (int kc = 0; kc < 2; ++kc) {
      f16x8 af[4], bf[4];
#pragma unroll
      for (int i = 0; i < 4; ++i) {
        const int ra = wm + i * 16 + frow;
        const int rb = wn + i * 16 + frow;
        af[i] = *(const f16x8*)(As + ra * 64 + ((((kc << 2) + lg) ^ (ra & 7)) << 3));
        bf[i] = *(const f16x8*)(Bs + rb * 64 + ((((kc << 2) + lg) ^ (rb & 7)) << 3));
      }
#pragma unroll
      for (int i = 0; i < 4; ++i)
#pragma unroll
        for (int j = 0; j < 4; ++j)
          acc[i][j] = mfma16(af[i], bf[j], acc[i][j]);
    }
    __syncthreads();
  }
}

// ------- fused: fp32->fp16 weight convert (blocks 0..12287) + LN1 (rest) ----
__global__ __launch_bounds__(256) void k_cvt_ln(const float* __restrict__ s0,
                                                const float* __restrict__ s1,
                                                const float* __restrict__ s2,
                                                const float* __restrict__ s3,
                                                f16* __restrict__ wout,
                                                const float* __restrict__ xin,
                                                const float* __restrict__ g,
                                                const float* __restrict__ bb,
                                                f16* __restrict__ xnout)
{
  __shared__ float red[8];
  const int tid = threadIdx.x;
  if (blockIdx.x < 12288) {
    const int i = blockIdx.x * 256 + tid;
    const float* src;
    int off;
    if (i < 786432)       { src = s0; off = 0; }
    else if (i < 1048576) { src = s1; off = 786432; }
    else if (i < 2097152) { src = s2; off = 1048576; }
    else                  { src = s3; off = 2097152; }
    const float4 f = ((const float4*)src)[i - off];
    f16x4 o; o[0] = (f16)f.x; o[1] = (f16)f.y; o[2] = (f16)f.z; o[3] = (f16)f.w;
    ((f16x4*)wout)[i] = o;
    return;
  }
  const size_t row = blockIdx.x - 12288;
  const float4 v = ((const float4*)(xin + row * 1024))[tid];
  float s  = v.x + v.y + v.z + v.w;
  float sq = v.x * v.x + v.y * v.y + v.z * v.z + v.w * v.w;
#pragma unroll
  for (int off = 32; off > 0; off >>= 1) { s += __shfl_xor(s, off); sq += __shfl_xor(sq, off); }
  if ((tid & 63) == 0) { red[tid >> 6] = s; red[4 + (tid >> 6)] = sq; }
  __syncthreads();
  s  = red[0] + red[1] + red[2] + red[3];
  sq = red[4] + red[5] + red[6] + red[7];
  const float mu = s * (1.0f / 1024.0f);
  const float rs = rsqrtf(sq * (1.0f / 1024.0f) - mu * mu + 1e-5f);
  const float4 gg = ((const float4*)g)[tid];
  const float4 bv = ((const float4*)bb)[tid];
  f16x4 o;
  o[0] = (f16)((v.x - mu) * rs * gg.x + bv.x);
  o[1] = (f16)((v.y - mu) * rs * gg.y + bv.y);
  o[2] = (f16)((v.z - mu) * rs * gg.z + bv.z);
  o[3] = (f16)((v.w - mu) * rs * gg.w + bv.w);
  ((f16x4*)(xnout + row * 1024))[tid] = o;
}

// ---------------- LayerNorm (1024 cols, 1 row/block) ----------------
__global__ __launch_bounds__(256) void k_ln(const float* __restrict__ xin,
                                            const float* __restrict__ g,
                                            const float* __restrict__ bb,
                                            f16* __restrict__ out)
{
  __shared__ float red[8];
  const int tid = threadIdx.x;
  const size_t row = blockIdx.x;
  const float4 v = ((const float4*)(xin + row * 1024))[tid];
  float s  = v.x + v.y + v.z + v.w;
  float sq = v.x * v.x + v.y * v.y + v.z * v.z + v.w * v.w;
#pragma unroll
  for (int off = 32; off > 0; off >>= 1) { s += __shfl_xor(s, off); sq += __shfl_xor(sq, off); }
  if ((tid & 63) == 0) { red[tid >> 6] = s; red[4 + (tid >> 6)] = sq; }
  __syncthreads();
  s  = red[0] + red[1] + red[2] + red[3];
  sq = red[4] + red[5] + red[6] + red[7];
  const float mu = s * (1.0f / 1024.0f);
  const float rs = rsqrtf(sq * (1.0f / 1024.0f) - mu * mu + 1e-5f);
  const float4 gg = ((const float4*)g)[tid];
  const float4 bv = ((const float4*)bb)[tid];
  f16x4 o;
  o[0] = (f16)((v.x - mu) * rs * gg.x + bv.x);
  o[1] = (f16)((v.y - mu) * rs * gg.y + bv.y);
  o[2] = (f16)((v.z - mu) * rs * gg.z + bv.z);
  o[3] = (f16)((v.w - mu) * rs * gg.w + bv.w);
  ((f16x4*)(out + row * 1024))[tid] = o;
}

// ---------------- QKV GEMM: [8192,1024] x [3072,1024]^T ----------------
__global__ __launch_bounds__(256) void k_qkv(const f16* __restrict__ xn,
                                             const f16* __restrict__ wq,
                                             f16* __restrict__ qb, f16* __restrict__ kb,
                                             f16* __restrict__ vT)
{
  __shared__ __align__(16) f16 As[8192], Bs[8192];
  f32x4 acc[4][4] = {};
  const int bm = blockIdx.x, bn = blockIdx.y;
  nt_core64(xn + (size_t)bm * 128 * 1024, wq + (size_t)bn * 128 * 1024,
            1024, 1024, 1024, As, Bs, acc);
  const int tid = threadIdx.x, lane = tid & 63, w = tid >> 6;
  const int r0 = bm * 128 + ((w >> 1) << 6) + ((lane >> 4) << 2);
  const int c0 = bn * 128 + ((w & 1) << 6);
  const int sec = (bn * 128) >> 10;
#pragma unroll
  for (int i = 0; i < 4; ++i) {
#pragma unroll
    for (int j = 0; j < 4; ++j) {
      const int o = c0 + j * 16 + (lane & 15);
      const int h = (o & 1023) >> 6, d = o & 63;
#pragma unroll
      for (int e = 0; e < 4; ++e) {
        const int m = r0 + i * 16 + e;
        const int b = m >> 10, n = m & 1023;
        const int bh = (b << 4) + h;
        const f16 val = (f16)acc[i][j][e];
        if (sec == 0)      qb[((size_t)bh * 1024 + n) * 64 + d] = val;
        else if (sec == 1) kb[((size_t)bh * 1024 + n) * 64 + d] = val;
        else               vT[((size_t)bh * 64 + d) * 1024 + n] = val;
      }
    }
  }
}

// ------- fused attention: 32 q-rows/block, attn store at kernel end ---------
// LDS P[32][1024] fp16, chunk-swizzled: (r,c) at r*1024 + (((c>>3)^(r&7))<<3)+(c&7)
__global__ __launch_bounds__(256) void k_attn(const f16* __restrict__ qb,
                                              const f16* __restrict__ kb,
                                              const f16* __restrict__ vT,
                                              float* __restrict__ attn,
                                              f16* __restrict__ y2)
{
  __shared__ __align__(16) f16 P[32 * 1024];   // 64 KB
  const int tid = threadIdx.x, lane = tid & 63, w = tid >> 6;
  const int lr = lane & 15, lg = lane >> 4;
  const int flat = blockIdx.y * 32 + blockIdx.x;
  const int id2 = (flat & 7) * 512 + (flat >> 3);       // XCD-chunked, bijective
  const int bh = id2 >> 5;
  const int m0 = (id2 & 31) * 32;
  const f16* Qb = qb + ((size_t)bh << 16);
  const f16* Kb = kb + ((size_t)bh << 16);
  const f16* Vt = vT + ((size_t)bh << 16);

  f16x8 qf[2][2];
#pragma unroll
  for (int i = 0; i < 2; ++i)
#pragma unroll
    for (int ks = 0; ks < 2; ++ks)
      qf[i][ks] = *(const f16x8*)(Qb + (size_t)(m0 + i * 16 + lr) * 64 + ks * 32 + lg * 8);

  // phase 1: S = Q K^T * 0.125 -> P_lds (fp16)
  for (int cc = 0; cc < 4; ++cc) {
    const int cb = (w << 8) + (cc << 6);
    f16x8 bf[4][2];
#pragma unroll
    for (int j = 0; j < 4; ++j)
#pragma unroll
      for (int ks = 0; ks < 2; ++ks)
        bf[j][ks] = *(const f16x8*)(Kb + (size_t)(cb + j * 16 + lr) * 64 + ks * 32 + lg * 8);
    f32x4 acc[2][4] = {};
#pragma unroll
    for (int i = 0; i < 2; ++i)
#pragma unroll
      for (int j = 0; j < 4; ++j) {
        acc[i][j] = mfma16(qf[i][0], bf[j][0], acc[i][j]);
        acc[i][j] = mfma16(qf[i][1], bf[j][1], acc[i][j]);
      }
#pragma unroll
    for (int i = 0; i < 2; ++i)
#pragma unroll
      for (int j = 0; j < 4; ++j)
#pragma unroll
        for (int e = 0; e < 4; ++e) {
          const int r = i * 16 + (lg << 2) + e;
          const int c = cb + j * 16 + lr;
          P[(r << 10) + (((c >> 3) ^ (r & 7)) << 3) + (c & 7)] = (f16)(acc[i][j][e] * 0.125f);
        }
  }
  __syncthreads();

  // phase 2: softmax. thread t: row t>>3, 16 chunks (t&7)+8q. Only the
  // normalized f16 P goes to LDS (what the barrier must order); raw exp (vv)
  // and inv stay in registers for the end-of-kernel fp32 store.
  const int r2 = tid >> 3;
  f16* Prow = P + (r2 << 10);
  const int rx = r2 & 7;
  f16x8 vv[16];
  float mrow = -1e30f;
#pragma unroll
  for (int q = 0; q < 16; ++q) {
    const int c = (tid & 7) + (q << 3);
    vv[q] = *(const f16x8*)(Prow + ((c ^ rx) << 3));
#pragma unroll
    for (int e = 0; e < 8; ++e) mrow = fmaxf(mrow, (float)vv[q][e]);
  }
  mrow = fmaxf(mrow, __shfl_xor(mrow, 1));
  mrow = fmaxf(mrow, __shfl_xor(mrow, 2));
  mrow = fmaxf(mrow, __shfl_xor(mrow, 4));
  float ssum = 0.f;
#pragma unroll
  for (int q = 0; q < 16; ++q) {
#pragma unroll
    for (int e = 0; e < 8; ++e) {
      const float ev = __expf((float)vv[q][e] - mrow);
      ssum += ev;
      vv[q][e] = (f16)ev;
    }
  }
  ssum += __shfl_xor(ssum, 1);
  ssum += __shfl_xor(ssum, 2);
  ssum += __shfl_xor(ssum, 4);
  const float inv = 1.0f / ssum;
#pragma unroll
  for (int q = 0; q < 16; ++q) {
    const int c = (tid & 7) + (q << 3);
    f16x8 nv;
#pragma unroll
    for (int e = 0; e < 8; ++e) nv[e] = (f16)((float)vv[q][e] * inv);
    *(f16x8*)(Prow + ((c ^ rx) << 3)) = nv;
  }
  __syncthreads();

  // phase 3: y = P @ V (V direct from global, L2-resident); no stores inside.
  const int dc = w << 4;
  f32x4 acc2[2] = {};
#pragma unroll 4
  for (int k0 = 0; k0 < 1024; k0 += 32) {
    const f16x8 bf = *(const f16x8*)(Vt + (size_t)(dc + lr) * 1024 + k0 + lg * 8);
#pragma unroll
    for (int i = 0; i < 2; ++i) {
      const int ra = i * 16 + lr;
      const int ch = (k0 >> 3) + lg;
      const f16x8 af = *(const f16x8*)(P + (ra << 10) + ((ch ^ (ra & 7)) << 3));
      acc2[i] = mfma16(af, bf, acc2[i]);
    }
  }
  const int b = bh >> 4, h = bh & 15;
#pragma unroll
  for (int i = 0; i < 2; ++i)
#pragma unroll
    for (int e = 0; e < 4; ++e) {
      const int rloc = i * 16 + (lg << 2) + e;
      y2[(size_t)(b * 1024 + m0 + rloc) * 1024 + (h << 6) + dc + lr] = (f16)acc2[i][e];
    }

  // end-of-kernel: fp32 attn output stores — nothing waits on these; they
  // drain in the background under other blocks' compute.
  float* Aout = attn + ((size_t)bh << 20) + ((size_t)(m0 + r2) << 10);
#pragma unroll
  for (int q = 0; q < 16; ++q) {
    const int c = (tid & 7) + (q << 3);
    f32x4 o0, o1;
    o0[0] = (float)vv[q][0] * inv; o0[1] = (float)vv[q][1] * inv;
    o0[2] = (float)vv[q][2] * inv; o0[3] = (float)vv[q][3] * inv;
    o1[0] = (float)vv[q][4] * inv; o1[1] = (float)vv[q][5] * inv;
    o1[2] = (float)vv[q][6] * inv; o1[3] = (float)vv[q][7] * inv;
    __builtin_nontemporal_store(o0, (f32x4*)(Aout + (c << 3)));
    __builtin_nontemporal_store(o1, (f32x4*)(Aout + (c << 3)) + 1);
  }
}

// ---------------- proj: xmid = y2 @ wproj^T + bproj + x ----------------
__global__ __launch_bounds__(256) void k_proj(const f16* __restrict__ y2,
                                              const f16* __restrict__ wp,
                                              const float* __restrict__ bproj,
                                              const float* __restrict__ x,
                                              float* __restrict__ xmid)
{
  __shared__ __align__(16) f16 As[8192], Bs[8192];
  f32x4 acc[4][4] = {};
  nt_core64(y2 + (size_t)blockIdx.x * 128 * 1024, wp + (size_t)blockIdx.y * 128 * 1024,
            1024, 1024, 1024, As, Bs, acc);
  const int tid = threadIdx.x, lane = tid & 63, w = tid >> 6;
  const int r0 = blockIdx.x * 128 + ((w >> 1) << 6) + ((lane >> 4) << 2);
  const int c0 = blockIdx.y * 128 + ((w & 1) << 6) + (lane & 15);
#pragma unroll
  for (int i = 0; i < 4; ++i)
#pragma unroll
    for (int j = 0; j < 4; ++j) {
      const int c = c0 + j * 16;
      const float bias = bproj[c];
#pragma unroll
      for (int e = 0; e < 4; ++e) {
        const size_t idx = (size_t)(r0 + i * 16 + e) * 1024 + c;
        xmid[idx] = acc[i][j][e] + bias + x[idx];
      }
    }
}

// ---------------- fc1: h = gelu(xn2 @ wfc1^T + bfc1) ----------------
__global__ __launch_bounds__(256) void k_fc1(const f16* __restrict__ xn,
                                             const f16* __restrict__ wf,
                                             const float* __restrict__ bfc1,
                                             f16* __restrict__ hb)
{
  __shared__ __align__(16) f16 As[8192], Bs[8192];
  f32x4 acc[4][4] = {};
  nt_core64(xn + (size_t)blockIdx.x * 128 * 1024, wf + (size_t)blockIdx.y * 128 * 1024,
            1024, 1024, 1024, As, Bs, acc);
  const int tid = threadIdx.x, lane = tid & 63, w = tid >> 6;
  const int r0 = blockIdx.x * 128 + ((w >> 1) << 6) + ((lane >> 4) << 2);
  const int c0 = blockIdx.y * 128 + ((w & 1) << 6) + (lane & 15);
#pragma unroll
  for (int i = 0; i < 4; ++i)
#pragma unroll
    for (int j = 0; j < 4; ++j) {
      const int c = c0 + j * 16;
      const float bias = bfc1[c];
#pragma unroll
      for (int e = 0; e < 4; ++e) {
        const float t = acc[i][j][e] + bias;
        hb[(size_t)(r0 + i * 16 + e) * 4096 + c] = (f16)gelu_f(t);
      }
    }
}

// ---------------- fc2: out = h @ wfc2^T + bfc2 + xmid ----------------
__global__ __launch_bounds__(256) void k_fc2(const f16* __restrict__ hb,
                                             const f16* __restrict__ wf,
                                             const float* __restrict__ bfc2,
                                             const float* __restrict__ xmid,
                                             float* __restrict__ out)
{
  __shared__ __align__(16) f16 As[8192], Bs[8192];
  f32x4 acc[4][4] = {};
  nt_core64(hb + (size_t)blockIdx.x * 128 * 4096, wf + (size_t)blockIdx.y * 128 * 4096,
            4096, 4096, 4096, As, Bs, acc);
  const int tid = threadIdx.x, lane = tid & 63, w = tid >> 6;
  const int r0 = blockIdx.x * 128 + ((w >> 1) << 6) + ((lane >> 4) << 2);
  const int c0 = blockIdx.y * 128 + ((w & 1) << 6) + (lane & 15);
#pragma unroll
  for (int i = 0; i < 4; ++i)
#pragma unroll
    for (int j = 0; j < 4; ++j) {
      const int c = c0 + j * 16;
      const float bias = bfc2[c];
#pragma unroll
      for (int e = 0; e < 4; ++e) {
        const size_t idx = (size_t)(r0 + i * 16 + e) * 1024 + c;
        out[idx] = acc[i][j][e] + bias + xmid[idx];
      }
    }
}

extern "C" void kernel_launch(void* const* d_in, const int* in_sizes, int n_in,
                              void* d_out, int out_size, void* d_ws, size_t ws_size,
                              hipStream_t stream)
{
  const float* x     = (const float*)d_in[0];
  const float* ln1g  = (const float*)d_in[1];
  const float* ln1b  = (const float*)d_in[2];
  const float* wqkv  = (const float*)d_in[3];
  const float* wproj = (const float*)d_in[4];
  const float* bproj = (const float*)d_in[5];
  const float* ln2g  = (const float*)d_in[6];
  const float* ln2b  = (const float*)d_in[7];
  const float* wfc1  = (const float*)d_in[8];
  const float* bfc1  = (const float*)d_in[9];
  const float* wfc2  = (const float*)d_in[10];
  const float* bfc2  = (const float*)d_in[11];

  char* ws = (char*)d_ws;
  f16* wqkv_h  = (f16*)(ws);                    //  6 MB  (contiguous cvt dest)
  f16* wproj_h = (f16*)(ws + 6291456);          //  2 MB
  f16* wfc1_h  = (f16*)(ws + 8388608);          //  8 MB
  f16* wfc2_h  = (f16*)(ws + 16777216);         //  8 MB
  f16* xn      = (f16*)(ws + 25165824);         // 16 MB (xn1, reused as xn2)
  f16* qb      = (f16*)(ws + 41943040);         // 16 MB
  f16* kb      = (f16*)(ws + 58720256);         // 16 MB
  f16* vT      = (f16*)(ws + 75497472);         // 16 MB
  f16* y2      = (f16*)(ws + 92274688);         // 16 MB
  float* xmid  = (float*)(ws + 109051904);      // 32 MB
  f16* hb      = (f16*)(ws + 41943040);         // 64 MB, aliases qb..y2 (dead by fc1)

  float* out_x = (float*)d_out;
  float* attn  = (float*)d_out + 8388608;

  k_cvt_ln<<<12288 + 8192, 256, 0, stream>>>(wqkv, wproj, wfc1, wfc2, wqkv_h,
                                             x, ln1g, ln1b, xn);
  k_qkv<<<dim3(64, 24), 256, 0, stream>>>(xn, wqkv_h, qb, kb, vT);
  k_attn<<<dim3(32, 128), 256, 0, stream>>>(qb, kb, vT, attn, y2);
  k_proj<<<dim3(64, 8), 256, 0, stream>>>(y2, wproj_h, bproj, x, xmid);
  k_ln<<<8192, 256, 0, stream>>>(xmid, ln2g, ln2b, xn);
  k_fc1<<<dim3(64, 32), 256, 0, stream>>>(xn, wfc1_h, bfc1, hb);
  k_fc2<<<dim3(64, 8), 256, 0, stream>>>(hb, wfc2_h, bfc2, xmid, out_x);
}

// Round 17
// 477.783 us; speedup vs baseline: 1.1567x; 1.0588x over previous
//
#include <hip/hip_runtime.h>
#include <cstdint>
#include <math.h>

// Transformer block: LN1 -> QKV -> fused MHA (attn probs = output[1]) -> proj+res
//                    -> LN2 -> GELU MLP + res -> output[0]
// GEMMs: fp16 MFMA 16x16x32, 128x128 tiles, BK=64, global_load_lds width-16
// staging, XOR chunk swizzle (pre-swizzled global source + swizzled ds_read).
// attn: 32 q-rows/block, 256 threads. R8 profile showed WRITE_SIZE 942MB vs
// 553MB actual output -> 1.7x write amplification: the old o0/o1 store pair
// wrote 16B per 32B span per instruction (partial sectors + NT = RMW at HBM).
// Fix: end-of-kernel readback loop re-reads normalized f16 P from LDS with
// contiguous ownership; each store instruction writes 128B full lines.

typedef _Float16 f16;
typedef _Float16 f16x4 __attribute__((ext_vector_type(4)));
typedef _Float16 f16x8 __attribute__((ext_vector_type(8)));
typedef float f32x4 __attribute__((ext_vector_type(4)));

#define DEV static __device__ __forceinline__

DEV void gload16(const void* g, void* l) {
  __builtin_amdgcn_global_load_lds(
      (__attribute__((address_space(1))) void*)(uintptr_t)g,
      (__attribute__((address_space(3))) void*)(uintptr_t)l, 16, 0, 0);
}

DEV f32x4 mfma16(f16x8 a, f16x8 b, f32x4 c) {
  return __builtin_amdgcn_mfma_f32_16x16x32_f16(a, b, c, 0, 0, 0);
}

// gelu via Abramowitz-Stegun 7.1.26 erf (|err| <= 1.5e-7)
DEV float gelu_f(float v) {
  const float a = fabsf(v) * 0.70710678118654752f;
  const float t = 1.0f / (1.0f + 0.3275911f * a);
  const float p = t * (0.254829592f + t * (-0.284496736f + t * (1.421413741f +
                  t * (-1.453152027f + t * 1.061405429f))));
  const float e = p * __expf(-a * a);
  const float erfv = v >= 0.f ? (1.f - e) : (e - 1.f);
  return 0.5f * v * (1.0f + erfv);
}

// ===== 128x128 NT GEMM core, BK=64: C_tile = A[128,K] * B[128,K]^T =========
DEV void nt_core64(const f16* __restrict__ A, const f16* __restrict__ B,
                   size_t lda, size_t ldb, int K, f16* As, f16* Bs,
                   f32x4 acc[4][4])
{
  const int tid  = threadIdx.x;
  const int lane = tid & 63;
  const int w    = tid >> 6;
  const int wm   = (w >> 1) << 6;
  const int wn   = (w & 1) << 6;
  const int frow = lane & 15;
  const int lg   = lane >> 4;

  const int srow0 = w * 32 + (lane >> 3);
  const int scol  = ((lane & 7) ^ ((lane >> 3) & 7)) << 3;
  const f16* Ab = A + (size_t)srow0 * lda + scol;
  const f16* Bb = B + (size_t)srow0 * ldb + scol;
  f16* la = As + w * 2048 + lane * 8;
  f16* lb = Bs + w * 2048 + lane * 8;

  for (int k0 = 0; k0 < K; k0 += 64) {
#pragma unroll
    for (int L = 0; L < 4; ++L)
      gload16(Ab + (size_t)(L * 8) * lda + k0, la + L * 512);
#pragma unroll
    for (int L = 0; L < 4; ++L)
      gload16(Bb + (size_t)(L * 8) * ldb + k0, lb + L * 512);
    __syncthreads();
#pragma unroll
    for (int kc = 0; kc < 2; ++kc) {
      f16x8 af[4], bf[4];
#pragma unroll
      for (int i = 0; i < 4; ++i) {
        const int ra = wm + i * 16 + frow;
        const int rb = wn + i * 16 + frow;
        af[i] = *(const f16x8*)(As + ra * 64 + ((((kc << 2) + lg) ^ (ra & 7)) << 3));
        bf[i] = *(const f16x8*)(Bs + rb * 64 + ((((kc << 2) + lg) ^ (rb & 7)) << 3));
      }
#pragma unroll
      for (int i = 0; i < 4; ++i)
#pragma unroll
        for (int j = 0; j < 4; ++j)
          acc[i][j] = mfma16(af[i], bf[j], acc[i][j]);
    }
    __syncthreads();
  }
}

// ------- fused: fp32->fp16 weight convert (blocks 0..12287) + LN1 (rest) ----
__global__ __launch_bounds__(256) void k_cvt_ln(const float* __restrict__ s0,
                                                const float* __restrict__ s1,
                                                const float* __restrict__ s2,
                                                const float* __restrict__ s3,
                                                f16* __restrict__ wout,
                                                const float* __restrict__ xin,
                                                const float* __restrict__ g,
                                                const float* __restrict__ bb,
                                                f16* __restrict__ xnout)
{
  __shared__ float red[8];
  const int tid = threadIdx.x;
  if (blockIdx.x < 12288) {
    const int i = blockIdx.x * 256 + tid;
    const float* src;
    int off;
    if (i < 786432)       { src = s0; off = 0; }
    else if (i < 1048576) { src = s1; off = 786432; }
    else if (i < 2097152) { src = s2; off = 1048576; }
    else                  { src = s3; off = 2097152; }
    const float4 f = ((const float4*)src)[i - off];
    f16x4 o; o[0] = (f16)f.x; o[1] = (f16)f.y; o[2] = (f16)f.z; o[3] = (f16)f.w;
    ((f16x4*)wout)[i] = o;
    return;
  }
  const size_t row = blockIdx.x - 12288;
  const float4 v = ((const float4*)(xin + row * 1024))[tid];
  float s  = v.x + v.y + v.z + v.w;
  float sq = v.x * v.x + v.y * v.y + v.z * v.z + v.w * v.w;
#pragma unroll
  for (int off = 32; off > 0; off >>= 1) { s += __shfl_xor(s, off); sq += __shfl_xor(sq, off); }
  if ((tid & 63) == 0) { red[tid >> 6] = s; red[4 + (tid >> 6)] = sq; }
  __syncthreads();
  s  = red[0] + red[1] + red[2] + red[3];
  sq = red[4] + red[5] + red[6] + red[7];
  const float mu = s * (1.0f / 1024.0f);
  const float rs = rsqrtf(sq * (1.0f / 1024.0f) - mu * mu + 1e-5f);
  const float4 gg = ((const float4*)g)[tid];
  const float4 bv = ((const float4*)bb)[tid];
  f16x4 o;
  o[0] = (f16)((v.x - mu) * rs * gg.x + bv.x);
  o[1] = (f16)((v.y - mu) * rs * gg.y + bv.y);
  o[2] = (f16)((v.z - mu) * rs * gg.z + bv.z);
  o[3] = (f16)((v.w - mu) * rs * gg.w + bv.w);
  ((f16x4*)(xnout + row * 1024))[tid] = o;
}

// ---------------- LayerNorm (1024 cols, 1 row/block) ----------------
__global__ __launch_bounds__(256) void k_ln(const float* __restrict__ xin,
                                            const float* __restrict__ g,
                                            const float* __restrict__ bb,
                                            f16* __restrict__ out)
{
  __shared__ float red[8];
  const int tid = threadIdx.x;
  const size_t row = blockIdx.x;
  const float4 v = ((const float4*)(xin + row * 1024))[tid];
  float s  = v.x + v.y + v.z + v.w;
  float sq = v.x * v.x + v.y * v.y + v.z * v.z + v.w * v.w;
#pragma unroll
  for (int off = 32; off > 0; off >>= 1) { s += __shfl_xor(s, off); sq += __shfl_xor(sq, off); }
  if ((tid & 63) == 0) { red[tid >> 6] = s; red[4 + (tid >> 6)] = sq; }
  __syncthreads();
  s  = red[0] + red[1] + red[2] + red[3];
  sq = red[4] + red[5] + red[6] + red[7];
  const float mu = s * (1.0f / 1024.0f);
  const float rs = rsqrtf(sq * (1.0f / 1024.0f) - mu * mu + 1e-5f);
  const float4 gg = ((const float4*)g)[tid];
  const float4 bv = ((const float4*)bb)[tid];
  f16x4 o;
  o[0] = (f16)((v.x - mu) * rs * gg.x + bv.x);
  o[1] = (f16)((v.y - mu) * rs * gg.y + bv.y);
  o[2] = (f16)((v.z - mu) * rs * gg.z + bv.z);
  o[3] = (f16)((v.w - mu) * rs * gg.w + bv.w);
  ((f16x4*)(out + row * 1024))[tid] = o;
}

// ---------------- QKV GEMM: [8192,1024] x [3072,1024]^T ----------------
__global__ __launch_bounds__(256) void k_qkv(const f16* __restrict__ xn,
                                             const f16* __restrict__ wq,
                                             f16* __restrict__ qb, f16* __restrict__ kb,
                                             f16* __restrict__ vT)
{
  __shared__ __align__(16) f16 As[8192], Bs[8192];
  f32x4 acc[4][4] = {};
  const int bm = blockIdx.x, bn = blockIdx.y;
  nt_core64(xn + (size_t)bm * 128 * 1024, wq + (size_t)bn * 128 * 1024,
            1024, 1024, 1024, As, Bs, acc);
  const int tid = threadIdx.x, lane = tid & 63, w = tid >> 6;
  const int r0 = bm * 128 + ((w >> 1) << 6) + ((lane >> 4) << 2);
  const int c0 = bn * 128 + ((w & 1) << 6);
  const int sec = (bn * 128) >> 10;
#pragma unroll
  for (int i = 0; i < 4; ++i) {
#pragma unroll
    for (int j = 0; j < 4; ++j) {
      const int o = c0 + j * 16 + (lane & 15);
      const int h = (o & 1023) >> 6, d = o & 63;
#pragma unroll
      for (int e = 0; e < 4; ++e) {
        const int m = r0 + i * 16 + e;
        const int b = m >> 10, n = m & 1023;
        const int bh = (b << 4) + h;
        const f16 val = (f16)acc[i][j][e];
        if (sec == 0)      qb[((size_t)bh * 1024 + n) * 64 + d] = val;
        else if (sec == 1) kb[((size_t)bh * 1024 + n) * 64 + d] = val;
        else               vT[((size_t)bh * 64 + d) * 1024 + n] = val;
      }
    }
  }
}

// ------- fused attention: 32 q-rows/block, lane-contiguous attn stores ------
// LDS P[32][1024] fp16, chunk-swizzled: (r,c) at r*1024 + (((c>>3)^(r&7))<<3)+(c&7)
__global__ __launch_bounds__(256) void k_attn(const f16* __restrict__ qb,
                                              const f16* __restrict__ kb,
                                              const f16* __restrict__ vT,
                                              float* __restrict__ attn,
                                              f16* __restrict__ y2)
{
  __shared__ __align__(16) f16 P[32 * 1024];   // 64 KB
  const int tid = threadIdx.x, lane = tid & 63, w = tid >> 6;
  const int lr = lane & 15, lg = lane >> 4;
  const int flat = blockIdx.y * 32 + blockIdx.x;
  const int id2 = (flat & 7) * 512 + (flat >> 3);       // XCD-chunked, bijective
  const int bh = id2 >> 5;
  const int m0 = (id2 & 31) * 32;
  const f16* Qb = qb + ((size_t)bh << 16);
  const f16* Kb = kb + ((size_t)bh << 16);
  const f16* Vt = vT + ((size_t)bh << 16);

  f16x8 qf[2][2];
#pragma unroll
  for (int i = 0; i < 2; ++i)
#pragma unroll
    for (int ks = 0; ks < 2; ++ks)
      qf[i][ks] = *(const f16x8*)(Qb + (size_t)(m0 + i * 16 + lr) * 64 + ks * 32 + lg * 8);

  // phase 1: S = Q K^T * 0.125 -> P_lds (fp16)
  for (int cc = 0; cc < 4; ++cc) {
    const int cb = (w << 8) + (cc << 6);
    f16x8 bf[4][2];
#pragma unroll
    for (int j = 0; j < 4; ++j)
#pragma unroll
      for (int ks = 0; ks < 2; ++ks)
        bf[j][ks] = *(const f16x8*)(Kb + (size_t)(cb + j * 16 + lr) * 64 + ks * 32 + lg * 8);
    f32x4 acc[2][4] = {};
#pragma unroll
    for (int i = 0; i < 2; ++i)
#pragma unroll
      for (int j = 0; j < 4; ++j) {
        acc[i][j] = mfma16(qf[i][0], bf[j][0], acc[i][j]);
        acc[i][j] = mfma16(qf[i][1], bf[j][1], acc[i][j]);
      }
#pragma unroll
    for (int i = 0; i < 2; ++i)
#pragma unroll
      for (int j = 0; j < 4; ++j)
#pragma unroll
        for (int e = 0; e < 4; ++e) {
          const int r = i * 16 + (lg << 2) + e;
          const int c = cb + j * 16 + lr;
          P[(r << 10) + (((c >> 3) ^ (r & 7)) << 3) + (c & 7)] = (f16)(acc[i][j][e] * 0.125f);
        }
  }
  __syncthreads();

  // phase 2: softmax. thread t: row t>>3, 16 chunks (t&7)+8q. Writes ONLY the
  // normalized f16 P to LDS; the fp32 attn store happens at kernel end via a
  // contiguous readback (vv dies here — no register retention).
  const int r2 = tid >> 3;
  f16* Prow = P + (r2 << 10);
  const int rx = r2 & 7;
  {
    f16x8 vv[16];
    float mrow = -1e30f;
#pragma unroll
    for (int q = 0; q < 16; ++q) {
      const int c = (tid & 7) + (q << 3);
      vv[q] = *(const f16x8*)(Prow + ((c ^ rx) << 3));
#pragma unroll
      for (int e = 0; e < 8; ++e) mrow = fmaxf(mrow, (float)vv[q][e]);
    }
    mrow = fmaxf(mrow, __shfl_xor(mrow, 1));
    mrow = fmaxf(mrow, __shfl_xor(mrow, 2));
    mrow = fmaxf(mrow, __shfl_xor(mrow, 4));
    float ssum = 0.f;
#pragma unroll
    for (int q = 0; q < 16; ++q) {
#pragma unroll
      for (int e = 0; e < 8; ++e) {
        const float ev = __expf((float)vv[q][e] - mrow);
        ssum += ev;
        vv[q][e] = (f16)ev;
      }
    }
    ssum += __shfl_xor(ssum, 1);
    ssum += __shfl_xor(ssum, 2);
    ssum += __shfl_xor(ssum, 4);
    const float inv = 1.0f / ssum;
#pragma unroll
    for (int q = 0; q < 16; ++q) {
      const int c = (tid & 7) + (q << 3);
      f16x8 nv;
#pragma unroll
      for (int e = 0; e < 8; ++e) nv[e] = (f16)((float)vv[q][e] * inv);
      *(f16x8*)(Prow + ((c ^ rx) << 3)) = nv;
    }
  }
  __syncthreads();

  // phase 3: y = P @ V (V direct from global, L2-resident)
  const int dc = w << 4;
  f32x4 acc2[2] = {};
#pragma unroll 4
  for (int k0 = 0; k0 < 1024; k0 += 32) {
    const f16x8 bf = *(const f16x8*)(Vt + (size_t)(dc + lr) * 1024 + k0 + lg * 8);
#pragma unroll
    for (int i = 0; i < 2; ++i) {
      const int ra = i * 16 + lr;
      const int ch = (k0 >> 3) + lg;
      const f16x8 af = *(const f16x8*)(P + (ra << 10) + ((ch ^ (ra & 7)) << 3));
      acc2[i] = mfma16(af, bf, acc2[i]);
    }
  }
  const int b = bh >> 4, h = bh & 15;
#pragma unroll
  for (int i = 0; i < 2; ++i)
#pragma unroll
    for (int e = 0; e < 4; ++e) {
      const int rloc = i * 16 + (lg << 2) + e;
      y2[(size_t)(b * 1024 + m0 + rloc) * 1024 + (h << 6) + dc + lr] = (f16)acc2[i][e];
    }

  // end: fp32 attn stores, LANE-CONTIGUOUS. Thread t, iter j covers float cols
  // [4*(t&7)+32j, +4); lanes 0-7 of a row write 128B contiguous per instruction
  // -> full lines, no partial-sector RMW. Values read back from normalized P.
  {
    const int s = tid & 7;
    float* ArowO = attn + ((size_t)bh << 20) + ((size_t)(m0 + r2) << 10);
#pragma unroll
    for (int j = 0; j < 32; ++j) {
      const int fc0 = 4 * s + 32 * j;
      const int cl = fc0 >> 3;
      const f16x4 v4 = *(const f16x4*)(Prow + ((cl ^ rx) << 3) + (fc0 & 7));
      f32x4 o;
      o[0] = (float)v4[0]; o[1] = (float)v4[1];
      o[2] = (float)v4[2]; o[3] = (float)v4[3];
      __builtin_nontemporal_store(o, (f32x4*)(ArowO + fc0));
    }
  }
}

// ---------------- proj: xmid = y2 @ wproj^T + bproj + x ----------------
__global__ __launch_bounds__(256) void k_proj(const f16* __restrict__ y2,
                                              const f16* __restrict__ wp,
                                              const float* __restrict__ bproj,
                                              const float* __restrict__ x,
                                              float* __restrict__ xmid)
{
  __shared__ __align__(16) f16 As[8192], Bs[8192];
  f32x4 acc[4][4] = {};
  nt_core64(y2 + (size_t)blockIdx.x * 128 * 1024, wp + (size_t)blockIdx.y * 128 * 1024,
            1024, 1024, 1024, As, Bs, acc);
  const int tid = threadIdx.x, lane = tid & 63, w = tid >> 6;
  const int r0 = blockIdx.x * 128 + ((w >> 1) << 6) + ((lane >> 4) << 2);
  const int c0 = blockIdx.y * 128 + ((w & 1) << 6) + (lane & 15);
#pragma unroll
  for (int i = 0; i < 4; ++i)
#pragma unroll
    for (int j = 0; j < 4; ++j) {
      const int c = c0 + j * 16;
      const float bias = bproj[c];
#pragma unroll
      for (int e = 0; e < 4; ++e) {
        const size_t idx = (size_t)(r0 + i * 16 + e) * 1024 + c;
        xmid[idx] = acc[i][j][e] + bias + x[idx];
      }
    }
}

// ---------------- fc1: h = gelu(xn2 @ wfc1^T + bfc1) ----------------
__global__ __launch_bounds__(256) void k_fc1(const f16* __restrict__ xn,
                                             const f16* __restrict__ wf,
                                             const float* __restrict__ bfc1,
                                             f16* __restrict__ hb)
{
  __shared__ __align__(16) f16 As[8192], Bs[8192];
  f32x4 acc[4][4] = {};
  nt_core64(xn + (size_t)blockIdx.x * 128 * 1024, wf + (size_t)blockIdx.y * 128 * 1024,
            1024, 1024, 1024, As, Bs, acc);
  const int tid = threadIdx.x, lane = tid & 63, w = tid >> 6;
  const int r0 = blockIdx.x * 128 + ((w >> 1) << 6) + ((lane >> 4) << 2);
  const int c0 = blockIdx.y * 128 + ((w & 1) << 6) + (lane & 15);
#pragma unroll
  for (int i = 0; i < 4; ++i)
#pragma unroll
    for (int j = 0; j < 4; ++j) {
      const int c = c0 + j * 16;
      const float bias = bfc1[c];
#pragma unroll
      for (int e = 0; e < 4; ++e) {
        const float t = acc[i][j][e] + bias;
        hb[(size_t)(r0 + i * 16 + e) * 4096 + c] = (f16)gelu_f(t);
      }
    }
}

// ---------------- fc2: out = h @ wfc2^T + bfc2 + xmid ----------------
__global__ __launch_bounds__(256) void k_fc2(const f16* __restrict__ hb,
                                             const f16* __restrict__ wf,
                                             const float* __restrict__ bfc2,
                                             const float* __restrict__ xmid,
                                             float* __restrict__ out)
{
  __shared__ __align__(16) f16 As[8192], Bs[8192];
  f32x4 acc[4][4] = {};
  nt_core64(hb + (size_t)blockIdx.x * 128 * 4096, wf + (size_t)blockIdx.y * 128 * 4096,
            4096, 4096, 4096, As, Bs, acc);
  const int tid = threadIdx.x, lane = tid & 63, w = tid >> 6;
  const int r0 = blockIdx.x * 128 + ((w >> 1) << 6) + ((lane >> 4) << 2);
  const int c0 = blockIdx.y * 128 + ((w & 1) << 6) + (lane & 15);
#pragma unroll
  for (int i = 0; i < 4; ++i)
#pragma unroll
    for (int j = 0; j < 4; ++j) {
      const int c = c0 + j * 16;
      const float bias = bfc2[c];
#pragma unroll
      for (int e = 0; e < 4; ++e) {
        const size_t idx = (size_t)(r0 + i * 16 + e) * 1024 + c;
        out[idx] = acc[i][j][e] + bias + xmid[idx];
      }
    }
}

extern "C" void kernel_launch(void* const* d_in, const int* in_sizes, int n_in,
                              void* d_out, int out_size, void* d_ws, size_t ws_size,
                              hipStream_t stream)
{
  const float* x     = (const float*)d_in[0];
  const float* ln1g  = (const float*)d_in[1];
  const float* ln1b  = (const float*)d_in[2];
  const float* wqkv  = (const float*)d_in[3];
  const float* wproj = (const float*)d_in[4];
  const float* bproj = (const float*)d_in[5];
  const float* ln2g  = (const float*)d_in[6];
  const float* ln2b  = (const float*)d_in[7];
  const float* wfc1  = (const float*)d_in[8];
  const float* bfc1  = (const float*)d_in[9];
  const float* wfc2  = (const float*)d_in[10];
  const float* bfc2  = (const float*)d_in[11];

  char* ws = (char*)d_ws;
  f16* wqkv_h  = (f16*)(ws);                    //  6 MB  (contiguous cvt dest)
  f16* wproj_h = (f16*)(ws + 6291456);          //  2 MB
  f16* wfc1_h  = (f16*)(ws + 8388608);          //  8 MB
  f16* wfc2_h  = (f16*)(ws + 16777216);         //  8 MB
  f16* xn      = (f16*)(ws + 25165824);         // 16 MB (xn1, reused as xn2)
  f16* qb      = (f16*)(ws + 41943040);         // 16 MB
  f16* kb      = (f16*)(ws + 58720256);         // 16 MB
  f16* vT      = (f16*)(ws + 75497472);         // 16 MB
  f16* y2      = (f16*)(ws + 92274688);         // 16 MB
  float* xmid  = (float*)(ws + 109051904);      // 32 MB
  f16* hb      = (f16*)(ws + 41943040);         // 64 MB, aliases qb..y2 (dead by fc1)

  float* out_x = (float*)d_out;
  float* attn  = (float*)d_out + 8388608;

  k_cvt_ln<<<12288 + 8192, 256, 0, stream>>>(wqkv, wproj, wfc1, wfc2, wqkv_h,
                                             x, ln1g, ln1b, xn);
  k_qkv<<<dim3(64, 24), 256, 0, stream>>>(xn, wqkv_h, qb, kb, vT);
  k_attn<<<dim3(32, 128), 256, 0, stream>>>(qb, kb, vT, attn, y2);
  k_proj<<<dim3(64, 8), 256, 0, stream>>>(y2, wproj_h, bproj, x, xmid);
  k_ln<<<8192, 256, 0, stream>>>(xmid, ln2g, ln2b, xn);
  k_fc1<<<dim3(64, 32), 256, 0, stream>>>(xn, wfc1_h, bfc1, hb);
  k_fc2<<<dim3(64, 8), 256, 0, stream>>>(hb, wfc2_h, bfc2, xmid, out_x);
}